// Round 9
// baseline (263.714 us; speedup 1.0000x reference)
//
#include <hip/hip_runtime.h>
#include <hip/hip_bf16.h>

#define NEXP 8
#define NEMB 1024
#define NTOK 8192
#define BM 128
#define BN 128
#define BK 64
#define NK  (NEMB / BK)
#define BLD_STRIPE 512

typedef __attribute__((ext_vector_type(8))) short  bf16x8;
typedef __attribute__((ext_vector_type(8))) unsigned short u16x8;
typedef __attribute__((ext_vector_type(4))) float  f32x4;

// ---- workspace layout (bytes) ----
#define XB_BYTES   (NTOK * NEMB * 2)
#define WB_BYTES   (NEXP * NEMB * NEMB * 2)
#define CNT_OFF    (XB_BYTES + WB_BYTES)          // counts0[8] then counts1[8]
#define LTOK0_OFF  (CNT_OFF + 256)
#define LWT0_OFF   (LTOK0_OFF + NEXP * NTOK * 4)
#define LTOK1_OFF  (LWT0_OFF + NEXP * NTOK * 4)
#define LWT1_OFF   (LTOK1_OFF + NEXP * NTOK * 4)
#define SELW_OFF   (LWT1_OFF + NEXP * NTOK * 4)   // 128 KB selw; reused as diag scratch

__device__ __forceinline__ unsigned short f2bf(float f) {
    unsigned u = __builtin_bit_cast(unsigned, f);
    unsigned r = (u + 0x7fffu + ((u >> 16) & 1u)) >> 16;
    return (unsigned short)r;
}

// ---------------- expert_w fp32 -> bf16 ----------------
__global__ void k_cvt_w(const float* __restrict__ w, unsigned short* __restrict__ wb) {
    int i = (blockIdx.x * blockDim.x + threadIdx.x) * 8;
    f32x4 v0 = *reinterpret_cast<const f32x4*>(w + i);
    f32x4 v1 = *reinterpret_cast<const f32x4*>(w + i + 4);
    u16x8 o;
#pragma unroll
    for (int j = 0; j < 4; ++j) { o[j] = f2bf(v0[j]); o[4 + j] = f2bf(v1[j]); }
    *reinterpret_cast<u16x8*>(wb + i) = o;
}

// ---------------- gating: pure streaming, no atomics ----------------
__global__ __launch_bounds__(256)
void k_gate(const float* __restrict__ x, const float* __restrict__ gw,
            unsigned short* __restrict__ xb, int4* __restrict__ selw) {
    int t = threadIdx.x, wave = t >> 6, lane = t & 63;
    int n = blockIdx.x * 4 + wave;

    const float* xr = x + (size_t)n * NEMB + lane * 16;
    f32x4 xv[4];
#pragma unroll
    for (int j = 0; j < 4; ++j) xv[j] = *reinterpret_cast<const f32x4*>(xr + j * 4);

    u16x8 o0, o1;
#pragma unroll
    for (int q = 0; q < 4; ++q) {
        o0[q] = f2bf(xv[0][q]); o0[4 + q] = f2bf(xv[1][q]);
        o1[q] = f2bf(xv[2][q]); o1[4 + q] = f2bf(xv[3][q]);
    }
    u16x8* xo = reinterpret_cast<u16x8*>(xb + (size_t)n * NEMB + lane * 16);
    xo[0] = o0; xo[1] = o1;

    float p[NEXP];
#pragma unroll
    for (int e = 0; e < NEXP; ++e) {
        const float* gr = gw + e * NEMB + lane * 16;
        f32x4 a = xv[0] * *reinterpret_cast<const f32x4*>(gr);
#pragma unroll
        for (int j = 1; j < 4; ++j) a += xv[j] * *reinterpret_cast<const f32x4*>(gr + j * 4);
        p[e] = a[0] + a[1] + a[2] + a[3];
    }
#pragma unroll
    for (int e = 0; e < NEXP; ++e) {
        float v = p[e];
#pragma unroll
        for (int m = 1; m < 64; m <<= 1) v += __shfl_xor(v, m, 64);
        p[e] = v;
    }
    if (lane == 0) {
        int e0 = 0; float b0 = p[0];
#pragma unroll
        for (int e = 1; e < NEXP; ++e) if (p[e] > b0) { b0 = p[e]; e0 = e; }
        int e1 = -1; float b1 = -3.4e38f;
#pragma unroll
        for (int e = 0; e < NEXP; ++e) if (e != e0 && p[e] > b1) { b1 = p[e]; e1 = e; }
        float ex = __expf(b1 - b0);
        float inv = 1.f / (1.f + ex);
        int4 s;
        s.x = e0; s.y = e1;
        s.z = __float_as_int(inv); s.w = __float_as_int(ex * inv);
        selw[n] = s;
    }
}

// ---------------- build primary (top-1) and secondary (top-2) per-expert lists ----------------
__global__ __launch_bounds__(256)
void k_build(const int4* __restrict__ selw, int* __restrict__ counts0, int* __restrict__ counts1,
             int* __restrict__ ltok0, float* __restrict__ lwt0,
             int* __restrict__ ltok1, float* __restrict__ lwt1) {
    int e = blockIdx.y;
    int n0 = blockIdx.x * BLD_STRIPE;
    __shared__ int lc0, lc1, b0, b1;
    __shared__ int   tk0[BLD_STRIPE], tk1[BLD_STRIPE];
    __shared__ float wv0[BLD_STRIPE], wv1[BLD_STRIPE];
    if (threadIdx.x == 0) { lc0 = 0; lc1 = 0; }
    __syncthreads();
    for (int i = threadIdx.x; i < BLD_STRIPE; i += 256) {
        int4 s = selw[n0 + i];
        if (s.x == e) {
            int p = atomicAdd(&lc0, 1);
            tk0[p] = n0 + i; wv0[p] = __int_as_float(s.z);
        }
        if (s.y == e) {
            int p = atomicAdd(&lc1, 1);
            tk1[p] = n0 + i; wv1[p] = __int_as_float(s.w);
        }
    }
    __syncthreads();
    if (threadIdx.x == 0) {
        b0 = atomicAdd(&counts0[e], lc0);
        b1 = atomicAdd(&counts1[e], lc1);
    }
    __syncthreads();
    for (int i = threadIdx.x; i < lc0; i += 256) {
        ltok0[e * NTOK + b0 + i] = tk0[i];
        lwt0[e * NTOK + b0 + i]  = wv0[i];
    }
    for (int i = threadIdx.x; i < lc1; i += 256) {
        ltok1[e * NTOK + b1 + i] = tk1[i];
        lwt1[e * NTOK + b1 + i]  = wv1[i];
    }
}

// ---------------- pad both lists to multiple of BM with (tok=-1, w=0) ----------------
__global__ void k_pad(const int* __restrict__ counts0, const int* __restrict__ counts1,
                      int* __restrict__ ltok0, float* __restrict__ lwt0,
                      int* __restrict__ ltok1, float* __restrict__ lwt1) {
    int e = blockIdx.x;
    int* lt   = blockIdx.y ? ltok1 : ltok0;
    float* lw = blockIdx.y ? lwt1 : lwt0;
    int c = blockIdx.y ? counts1[e] : counts0[e];
    int cp = (c + BM - 1) & ~(BM - 1);
    for (int i = c + threadIdx.x; i < cp; i += blockDim.x) {
        lt[e * NTOK + i] = -1;
        lw[e * NTOK + i] = 0.f;
    }
}

// ---------------- grouped gathered GEMM (R6 production kernel, unchanged) ----------------
__global__ __launch_bounds__(256)
void k_gemm(const unsigned short* __restrict__ xb, const unsigned short* __restrict__ wb,
            const int* __restrict__ counts, const int* __restrict__ ltok,
            const float* __restrict__ lwt, float* __restrict__ out, int accum) {
    int e = blockIdx.z;
    int cnt = counts[e];
    int rb = blockIdx.y;
    if (rb * BM >= cnt) return;
    int cb = blockIdx.x;

    __shared__ unsigned short As[2][BM * BK];   // 2 x 16 KB
    __shared__ unsigned short Bs[2][BN * BK];   // 2 x 16 KB
    __shared__ int   tokS[BM];
    __shared__ float wS[BM];

    int t = threadIdx.x;
    int lane = t & 63, wave = t >> 6;
    int wr = wave >> 1, wc = wave & 1;

    if (t < BM) {
        tokS[t] = ltok[e * NTOK + rb * BM + t];
        wS[t]   = lwt[e * NTOK + rb * BM + t];
    }

    const unsigned short* aSrc[4];
    const unsigned short* bSrc[4];
    int ldsOff[4];
#pragma unroll
    for (int i = 0; i < 4; ++i) {
        int idx = i * 256 + t;
        int r   = idx >> 3;
        int c   = idx & 7;
        int csw = c ^ (r & 7);
        int tok = ltok[e * NTOK + rb * BM + r];
        int tokc = tok < 0 ? 0 : tok;
        aSrc[i] = xb + (size_t)tokc * NEMB + csw * 8;
        bSrc[i] = wb + (size_t)e * NEMB * NEMB + (size_t)(cb * BN + r) * NEMB + csw * 8;
        ldsOff[i] = (i * 256 + wave * 64) * 8;
    }

#define STAGE(buf, kk)                                                              \
    {                                                                               \
        _Pragma("unroll")                                                           \
        for (int i = 0; i < 4; ++i) {                                               \
            __builtin_amdgcn_global_load_lds(                                       \
                (const __attribute__((address_space(1))) void*)(aSrc[i] + (kk) * BK),\
                (__attribute__((address_space(3))) void*)(&As[buf][0] + ldsOff[i]), \
                16, 0, 0);                                                          \
            __builtin_amdgcn_global_load_lds(                                       \
                (const __attribute__((address_space(1))) void*)(bSrc[i] + (kk) * BK),\
                (__attribute__((address_space(3))) void*)(&Bs[buf][0] + ldsOff[i]), \
                16, 0, 0);                                                          \
        }                                                                           \
    }

    f32x4 acc[4][4];
#pragma unroll
    for (int m = 0; m < 4; ++m)
#pragma unroll
        for (int n = 0; n < 4; ++n) acc[m][n] = (f32x4){0.f, 0.f, 0.f, 0.f};

    int fr = lane & 15, fq = lane >> 4, fs = fr & 7;

    STAGE(0, 0);
    __syncthreads();

    for (int kk = 0; kk < NK; ++kk) {
        int cur = kk & 1;
        if (kk + 1 < NK) STAGE(cur ^ 1, kk + 1);

#pragma unroll
        for (int ks = 0; ks < 2; ++ks) {
            int ch = (fq + 4 * ks) ^ fs;
            bf16x8 af[4], bfr[4];
#pragma unroll
            for (int m = 0; m < 4; ++m) {
                int row = wr * 64 + m * 16 + fr;
                af[m] = *reinterpret_cast<const bf16x8*>(&As[cur][0] + row * BK + ch * 8);
            }
#pragma unroll
            for (int n = 0; n < 4; ++n) {
                int row = wc * 64 + n * 16 + fr;
                bfr[n] = *reinterpret_cast<const bf16x8*>(&Bs[cur][0] + row * BK + ch * 8);
            }
#pragma unroll
            for (int m = 0; m < 4; ++m)
#pragma unroll
                for (int n = 0; n < 4; ++n)
                    acc[m][n] = __builtin_amdgcn_mfma_f32_16x16x32_bf16(
                        af[m], bfr[n], acc[m][n], 0, 0, 0);
        }
        __syncthreads();
    }
#undef STAGE

#pragma unroll
    for (int m = 0; m < 4; ++m) {
#pragma unroll
        for (int jj = 0; jj < 4; ++jj) {
            int row  = wr * 64 + m * 16 + fq * 4 + jj;
            int tok  = tokS[row];
            if (tok < 0) continue;
            float wgt = wS[row];
            float* orow = out + (size_t)tok * NEMB + cb * BN + wc * 64 + fr;
            if (accum) {
#pragma unroll
                for (int n = 0; n < 4; ++n)
                    orow[n * 16] += wgt * acc[m][n][jj];
            } else {
#pragma unroll
                for (int n = 0; n < 4; ++n)
                    orow[n * 16] = wgt * acc[m][n][jj];
            }
        }
    }
}

// ================= DIAGNOSTICS (write to scratch; decompose k_gemm's time) =================

// compute-only share: stage tile 0 once, then AMP x NK iters of {ds_read + MFMA + barrier}
__global__ __launch_bounds__(256)
void k_diag_comp(const unsigned short* __restrict__ xb, const unsigned short* __restrict__ wb,
                 const int* __restrict__ counts, const int* __restrict__ ltok,
                 float* __restrict__ dout) {
    int e = blockIdx.z;
    int cnt = counts[e];
    int rb = blockIdx.y;
    if (rb * BM >= cnt) return;
    int cb = blockIdx.x;

    __shared__ unsigned short As[2][BM * BK];
    __shared__ unsigned short Bs[2][BN * BK];

    int t = threadIdx.x;
    int lane = t & 63, wave = t >> 6;
    int wr = wave >> 1, wc = wave & 1;

    const unsigned short* aSrc[4];
    const unsigned short* bSrc[4];
    int ldsOff[4];
#pragma unroll
    for (int i = 0; i < 4; ++i) {
        int idx = i * 256 + t;
        int r   = idx >> 3;
        int csw = (idx & 7) ^ (r & 7);
        int tok = ltok[e * NTOK + rb * BM + r];
        int tokc = tok < 0 ? 0 : tok;
        aSrc[i] = xb + (size_t)tokc * NEMB + csw * 8;
        bSrc[i] = wb + (size_t)e * NEMB * NEMB + (size_t)(cb * BN + r) * NEMB + csw * 8;
        ldsOff[i] = (i * 256 + wave * 64) * 8;
    }
    // stage both buffers once (content then reused as stale data)
#pragma unroll
    for (int i = 0; i < 4; ++i) {
        __builtin_amdgcn_global_load_lds(
            (const __attribute__((address_space(1))) void*)(aSrc[i]),
            (__attribute__((address_space(3))) void*)(&As[0][0] + ldsOff[i]), 16, 0, 0);
        __builtin_amdgcn_global_load_lds(
            (const __attribute__((address_space(1))) void*)(bSrc[i]),
            (__attribute__((address_space(3))) void*)(&Bs[0][0] + ldsOff[i]), 16, 0, 0);
        __builtin_amdgcn_global_load_lds(
            (const __attribute__((address_space(1))) void*)(aSrc[i] + BK),
            (__attribute__((address_space(3))) void*)(&As[1][0] + ldsOff[i]), 16, 0, 0);
        __builtin_amdgcn_global_load_lds(
            (const __attribute__((address_space(1))) void*)(bSrc[i] + BK),
            (__attribute__((address_space(3))) void*)(&Bs[1][0] + ldsOff[i]), 16, 0, 0);
    }
    __syncthreads();

    f32x4 acc[4][4];
#pragma unroll
    for (int m = 0; m < 4; ++m)
#pragma unroll
        for (int n = 0; n < 4; ++n) acc[m][n] = (f32x4){0.f, 0.f, 0.f, 0.f};

    int fr = lane & 15, fq = lane >> 4, fs = fr & 7;

    for (int rep = 0; rep < 3; ++rep) {
        for (int kk = 0; kk < NK; ++kk) {
            int cur = kk & 1;
#pragma unroll
            for (int ks = 0; ks < 2; ++ks) {
                int ch = (fq + 4 * ks) ^ fs;
                bf16x8 af[4], bfr[4];
#pragma unroll
                for (int m = 0; m < 4; ++m)
                    af[m] = *reinterpret_cast<const bf16x8*>(
                        &As[cur][0] + (wr * 64 + m * 16 + fr) * BK + ch * 8);
#pragma unroll
                for (int n = 0; n < 4; ++n)
                    bfr[n] = *reinterpret_cast<const bf16x8*>(
                        &Bs[cur][0] + (wc * 64 + n * 16 + fr) * BK + ch * 8);
#pragma unroll
                for (int m = 0; m < 4; ++m)
#pragma unroll
                    for (int n = 0; n < 4; ++n)
                        acc[m][n] = __builtin_amdgcn_mfma_f32_16x16x32_bf16(
                            af[m], bfr[n], acc[m][n], 0, 0, 0);
            }
            __syncthreads();
        }
    }
    // keep alive: wave-reduce checksum, one store per wave
    float s = 0.f;
#pragma unroll
    for (int m = 0; m < 4; ++m)
#pragma unroll
        for (int n = 0; n < 4; ++n) s += acc[m][n][0] + acc[m][n][1] + acc[m][n][2] + acc[m][n][3];
#pragma unroll
    for (int mk = 1; mk < 64; mk <<= 1) s += __shfl_xor(s, mk, 64);
    if (lane == 0) {
        int bid = (blockIdx.z * gridDim.y + blockIdx.y) * gridDim.x + blockIdx.x;
        dout[bid * 4 + wave] = s;
    }
}

// stage-only share: AMP x NK iters of {8 global_load_lds + barrier}; no ds_read/MFMA
__global__ __launch_bounds__(256)
void k_diag_stage(const unsigned short* __restrict__ xb, const unsigned short* __restrict__ wb,
                  const int* __restrict__ counts, const int* __restrict__ ltok,
                  float* __restrict__ dout) {
    int e = blockIdx.z;
    int cnt = counts[e];
    int rb = blockIdx.y;
    if (rb * BM >= cnt) return;
    int cb = blockIdx.x;

    __shared__ unsigned short As[2][BM * BK];
    __shared__ unsigned short Bs[2][BN * BK];

    int t = threadIdx.x;
    int lane = t & 63, wave = t >> 6;

    const unsigned short* aSrc[4];
    const unsigned short* bSrc[4];
    int ldsOff[4];
#pragma unroll
    for (int i = 0; i < 4; ++i) {
        int idx = i * 256 + t;
        int r   = idx >> 3;
        int csw = (idx & 7) ^ (r & 7);
        int tok = ltok[e * NTOK + rb * BM + r];
        int tokc = tok < 0 ? 0 : tok;
        aSrc[i] = xb + (size_t)tokc * NEMB + csw * 8;
        bSrc[i] = wb + (size_t)e * NEMB * NEMB + (size_t)(cb * BN + r) * NEMB + csw * 8;
        ldsOff[i] = (i * 256 + wave * 64) * 8;
    }

    for (int rep = 0; rep < 2; ++rep) {
        for (int kk = 0; kk < NK; ++kk) {
            int cur = kk & 1;
#pragma unroll
            for (int i = 0; i < 4; ++i) {
                __builtin_amdgcn_global_load_lds(
                    (const __attribute__((address_space(1))) void*)(aSrc[i] + kk * BK),
                    (__attribute__((address_space(3))) void*)(&As[cur][0] + ldsOff[i]), 16, 0, 0);
                __builtin_amdgcn_global_load_lds(
                    (const __attribute__((address_space(1))) void*)(bSrc[i] + kk * BK),
                    (__attribute__((address_space(3))) void*)(&Bs[cur][0] + ldsOff[i]), 16, 0, 0);
            }
            __syncthreads();
        }
    }
    // keep alive: read back a little of what was staged
    float s = (float)As[0][t] + (float)Bs[0][t] + (float)As[1][t] + (float)Bs[1][t];
#pragma unroll
    for (int mk = 1; mk < 64; mk <<= 1) s += __shfl_xor(s, mk, 64);
    if (lane == 0) {
        int bid = (blockIdx.z * gridDim.y + blockIdx.y) * gridDim.x + blockIdx.x;
        dout[16384 + bid * 4 + wave] = s;
    }
}

extern "C" void kernel_launch(void* const* d_in, const int* in_sizes, int n_in,
                              void* d_out, int out_size, void* d_ws, size_t ws_size,
                              hipStream_t stream) {
    const float* x  = (const float*)d_in[0];
    const float* gw = (const float*)d_in[1];
    const float* ew = (const float*)d_in[2];
    float* out = (float*)d_out;

    char* ws = (char*)d_ws;
    unsigned short* xb = (unsigned short*)(ws);
    unsigned short* wb = (unsigned short*)(ws + XB_BYTES);
    int*   counts0 = (int*)(ws + CNT_OFF);
    int*   counts1 = counts0 + 8;
    int*   ltok0   = (int*)(ws + LTOK0_OFF);
    float* lwt0    = (float*)(ws + LWT0_OFF);
    int*   ltok1   = (int*)(ws + LTOK1_OFF);
    float* lwt1    = (float*)(ws + LWT1_OFF);
    int4*  selw    = (int4*)(ws + SELW_OFF);
    float* diag    = (float*)(ws + SELW_OFF);   // selw reused after k_build consumes it

    hipMemsetAsync(counts0, 0, 16 * sizeof(int), stream);

    k_cvt_w<<<4096, 256, 0, stream>>>(ew, wb);
    k_gate<<<NTOK / 4, 256, 0, stream>>>(x, gw, xb, selw);
    k_build<<<dim3(NTOK / BLD_STRIPE, NEXP), 256, 0, stream>>>(selw, counts0, counts1,
                                                               ltok0, lwt0, ltok1, lwt1);
    k_pad<<<dim3(8, 2), 128, 0, stream>>>(counts0, counts1, ltok0, lwt0, ltok1, lwt1);
    // production passes (R6 structure, 150 µs total)
    k_gemm<<<dim3(NEMB / BN, NTOK / BM, NEXP), 256, 0, stream>>>(
        xb, wb, counts0, ltok0, lwt0, out, 0);
    k_gemm<<<dim3(NEMB / BN, NTOK / BM, NEXP), 256, 0, stream>>>(
        xb, wb, counts1, ltok1, lwt1, out, 1);
    // diagnostics (after production; write to scratch only)
    k_diag_comp<<<dim3(NEMB / BN, NTOK / BM, NEXP), 256, 0, stream>>>(
        xb, wb, counts0, ltok0, diag);
    k_diag_stage<<<dim3(NEMB / BN, NTOK / BM, NEXP), 256, 0, stream>>>(
        xb, wb, counts0, ltok0, diag);
}

// Round 10
// 146.408 us; speedup vs baseline: 1.8012x; 1.8012x over previous
//
#include <hip/hip_runtime.h>
#include <hip/hip_bf16.h>

#define NEXP 8
#define NEMB 1024
#define NTOK 8192
#define BM 256
#define BN 256
#define BK 64
#define NK  (NEMB / BK)   // 16 K-tiles
#define NIT (NK / 2)      // 8 iterations, 2 K-tiles each
#define BLD_STRIPE 512

typedef __attribute__((ext_vector_type(8))) short  bf16x8;
typedef __attribute__((ext_vector_type(8))) unsigned short u16x8;
typedef __attribute__((ext_vector_type(4))) float  f32x4;

// ---- workspace layout (bytes) ----
#define XB_BYTES   (NTOK * NEMB * 2)
#define WB_BYTES   (NEXP * NEMB * NEMB * 2)
#define CNT_OFF    (XB_BYTES + WB_BYTES)
#define LTOK_OFF   (CNT_OFF + 256)
#define LWT_OFF    (LTOK_OFF + NEXP * NTOK * 4)
#define SELW_OFF   (LWT_OFF + NEXP * NTOK * 4)

__device__ __forceinline__ unsigned short f2bf(float f) {
    unsigned u = __builtin_bit_cast(unsigned, f);
    unsigned r = (u + 0x7fffu + ((u >> 16) & 1u)) >> 16;
    return (unsigned short)r;
}

// ---------------- expert_w fp32 -> bf16 ----------------
__global__ void k_cvt_w(const float* __restrict__ w, unsigned short* __restrict__ wb) {
    int i = (blockIdx.x * blockDim.x + threadIdx.x) * 8;
    f32x4 v0 = *reinterpret_cast<const f32x4*>(w + i);
    f32x4 v1 = *reinterpret_cast<const f32x4*>(w + i + 4);
    u16x8 o;
#pragma unroll
    for (int j = 0; j < 4; ++j) { o[j] = f2bf(v0[j]); o[4 + j] = f2bf(v1[j]); }
    *reinterpret_cast<u16x8*>(wb + i) = o;
}

// ---------------- gating: pure streaming, no atomics ----------------
__global__ __launch_bounds__(256)
void k_gate(const float* __restrict__ x, const float* __restrict__ gw,
            unsigned short* __restrict__ xb, int4* __restrict__ selw) {
    int t = threadIdx.x, wave = t >> 6, lane = t & 63;
    int n = blockIdx.x * 4 + wave;

    const float* xr = x + (size_t)n * NEMB + lane * 16;
    f32x4 xv[4];
#pragma unroll
    for (int j = 0; j < 4; ++j) xv[j] = *reinterpret_cast<const f32x4*>(xr + j * 4);

    u16x8 o0, o1;
#pragma unroll
    for (int q = 0; q < 4; ++q) {
        o0[q] = f2bf(xv[0][q]); o0[4 + q] = f2bf(xv[1][q]);
        o1[q] = f2bf(xv[2][q]); o1[4 + q] = f2bf(xv[3][q]);
    }
    u16x8* xo = reinterpret_cast<u16x8*>(xb + (size_t)n * NEMB + lane * 16);
    xo[0] = o0; xo[1] = o1;

    float p[NEXP];
#pragma unroll
    for (int e = 0; e < NEXP; ++e) {
        const float* gr = gw + e * NEMB + lane * 16;
        f32x4 a = xv[0] * *reinterpret_cast<const f32x4*>(gr);
#pragma unroll
        for (int j = 1; j < 4; ++j) a += xv[j] * *reinterpret_cast<const f32x4*>(gr + j * 4);
        p[e] = a[0] + a[1] + a[2] + a[3];
    }
#pragma unroll
    for (int e = 0; e < NEXP; ++e) {
        float v = p[e];
#pragma unroll
        for (int m = 1; m < 64; m <<= 1) v += __shfl_xor(v, m, 64);
        p[e] = v;
    }
    if (lane == 0) {
        int e0 = 0; float b0 = p[0];
#pragma unroll
        for (int e = 1; e < NEXP; ++e) if (p[e] > b0) { b0 = p[e]; e0 = e; }
        int e1 = -1; float b1 = -3.4e38f;
#pragma unroll
        for (int e = 0; e < NEXP; ++e) if (e != e0 && p[e] > b1) { b1 = p[e]; e1 = e; }
        float ex = __expf(b1 - b0);
        float inv = 1.f / (1.f + ex);
        int4 s;
        s.x = e0; s.y = e1;
        s.z = __float_as_int(inv); s.w = __float_as_int(ex * inv);
        selw[n] = s;
    }
}

// ---------------- build combined per-expert token list ----------------
__global__ __launch_bounds__(256)
void k_build(const int4* __restrict__ selw, int* __restrict__ counts,
             int* __restrict__ ltok, float* __restrict__ lwt) {
    int e = blockIdx.y;
    int n0 = blockIdx.x * BLD_STRIPE;
    __shared__ int lcnt, base;
    __shared__ int   toks[BLD_STRIPE];
    __shared__ float wts[BLD_STRIPE];
    if (threadIdx.x == 0) lcnt = 0;
    __syncthreads();
    for (int i = threadIdx.x; i < BLD_STRIPE; i += 256) {
        int4 s = selw[n0 + i];
        if (s.x == e) {
            int p = atomicAdd(&lcnt, 1);
            toks[p] = n0 + i; wts[p] = __int_as_float(s.z);
        }
        if (s.y == e) {
            int p = atomicAdd(&lcnt, 1);
            toks[p] = n0 + i; wts[p] = __int_as_float(s.w);
        }
    }
    __syncthreads();
    if (threadIdx.x == 0) base = atomicAdd(&counts[e], lcnt);
    __syncthreads();
    for (int i = threadIdx.x; i < lcnt; i += 256) {
        ltok[e * NTOK + base + i] = toks[i];
        lwt[e * NTOK + base + i]  = wts[i];
    }
}

// ---------------- pad list to multiple of BM with (tok=-1, w=0) ----------------
__global__ void k_pad(const int* __restrict__ counts, int* __restrict__ ltok,
                      float* __restrict__ lwt) {
    int e = blockIdx.x;
    int c = counts[e];
    int cp = (c + BM - 1) & ~(BM - 1);
    for (int i = c + threadIdx.x; i < cp; i += blockDim.x) {
        ltok[e * NTOK + i] = -1;
        lwt[e * NTOK + i]  = 0.f;
    }
}

// ---------------- grouped gathered GEMM: 8-phase counted-vmcnt schedule ----------------
// 256x256 tile, BK=64, 8 waves (2M x 4N), interleaved row maps:
//   A frag m row = m*32 + wr*16 + fr   (mh0 = rows 0-127)
//   B frag n row = n*64 + wc*16 + fr   (nh0 = rows 0-127)
// Quadrants {mh x nh}, af/bf kept in regs across phases (24 ds_read_b128/K-tile).
// Stage order (1 half-tile = 2 loads/thread per phase):
//   P1:Ah1(k1) P2:Ah0(k0+2) P3:Bh0(k0+2) P4:Ah1(k0+2) P5:Bh1(k0+2)
//   P6:Ah0(k1+2) P7:Bh0(k1+2) P8:Bh1(k1+2)      [k0=2i even->buf0, odd->buf1]
// Every stage target: last read >=1 phase earlier (write-safe via end barriers).
// Every read's producer: >=3 phases old; vmcnt(6)@P4,P8 -> all but newest 6
// loads landed -> producer landed (derived; matches template).
// Swizzle: LDS chunk (r,c) holds global chunk c^(r&7); read chunk (fq+4ks)^(fr&7).
__global__ __launch_bounds__(512, 2)
void k_gemm(const unsigned short* __restrict__ xb, const unsigned short* __restrict__ wb,
            const int* __restrict__ counts, const int* __restrict__ ltok,
            const float* __restrict__ lwt, float* __restrict__ out) {
    int e  = blockIdx.z;
    int rb = blockIdx.y;
    int cb = blockIdx.x;
    if (rb * BM >= counts[e]) return;

    __shared__ unsigned short As[2][BM * BK];   // 2 x 32 KB
    __shared__ unsigned short Bs[2][BN * BK];   // 2 x 32 KB
    __shared__ int   tokS[BM];
    __shared__ float wS[BM];

    int t = threadIdx.x, lane = t & 63, wave = t >> 6;
    int wr = wave >> 2, wc = wave & 3;
    int fr = lane & 15, fq = lane >> 4, fs = fr & 7;
    int pk0 = fq ^ fs, pk1 = (fq + 4) ^ fs;

    if (t < BM) {
        tokS[t] = ltok[e * NTOK + rb * BM + t];
        wS[t]   = lwt[e * NTOK + rb * BM + t];
    }

    // staging sources: 4 rows per thread (j*64 + t>>3), chunk swizzled
    int c0 = t & 7, r0 = t >> 3;
    int csw = c0 ^ (r0 & 7);
    const unsigned short* aS[4];
    const unsigned short* bS[4];
#pragma unroll
    for (int j = 0; j < 4; ++j) {
        int row = j * 64 + r0;
        int tok = ltok[e * NTOK + rb * BM + row];
        int tokc = tok < 0 ? 0 : tok;
        aS[j] = xb + (size_t)tokc * NEMB + csw * 8;
        bS[j] = wb + (size_t)e * NEMB * NEMB + (size_t)(cb * BN + row) * NEMB + csw * 8;
    }
    int off0 = wave * 512;          // elems; HW adds lane*16B
    int off1 = 4096 + wave * 512;

#define GLL(src, dst)                                                                \
    __builtin_amdgcn_global_load_lds(                                                \
        (const __attribute__((address_space(1))) void*)(src),                        \
        (__attribute__((address_space(3))) void*)(dst), 16, 0, 0)
#define STG_A(buf, h, kt) if ((kt) < NK) {                                           \
    GLL(aS[(h)*2 + 0] + (kt)*BK, &As[buf][(h)*8192 + off0]);                         \
    GLL(aS[(h)*2 + 1] + (kt)*BK, &As[buf][(h)*8192 + off1]); }
#define STG_B(buf, h, kt) if ((kt) < NK) {                                           \
    GLL(bS[(h)*2 + 0] + (kt)*BK, &Bs[buf][(h)*8192 + off0]);                         \
    GLL(bS[(h)*2 + 1] + (kt)*BK, &Bs[buf][(h)*8192 + off1]); }

#define LDA(mh, buf) { _Pragma("unroll")                                             \
    for (int m = 0; m < 4; ++m) {                                                    \
        int row = ((mh)*4 + m)*32 + wr*16 + fr;                                      \
        af[m][0] = *reinterpret_cast<const bf16x8*>(&As[buf][row*BK + pk0*8]);       \
        af[m][1] = *reinterpret_cast<const bf16x8*>(&As[buf][row*BK + pk1*8]); } }
#define LDB(dst, nh, buf) { _Pragma("unroll")                                        \
    for (int n = 0; n < 2; ++n) {                                                    \
        int row = ((nh)*2 + n)*64 + wc*16 + fr;                                      \
        dst[n][0] = *reinterpret_cast<const bf16x8*>(&Bs[buf][row*BK + pk0*8]);      \
        dst[n][1] = *reinterpret_cast<const bf16x8*>(&Bs[buf][row*BK + pk1*8]); } }
#define MM(mh, nh, bfx) { _Pragma("unroll")                                          \
    for (int m = 0; m < 4; ++m) { _Pragma("unroll")                                  \
        for (int n = 0; n < 2; ++n) {                                                \
            acc[(mh)*4+m][(nh)*2+n] = __builtin_amdgcn_mfma_f32_16x16x32_bf16(       \
                af[m][0], bfx[n][0], acc[(mh)*4+m][(nh)*2+n], 0, 0, 0);              \
            acc[(mh)*4+m][(nh)*2+n] = __builtin_amdgcn_mfma_f32_16x16x32_bf16(       \
                af[m][1], bfx[n][1], acc[(mh)*4+m][(nh)*2+n], 0, 0, 0); } } }
#define BAR   __builtin_amdgcn_s_barrier()
#define LGKM0 asm volatile("s_waitcnt lgkmcnt(0)" ::: "memory")
#define VM6   asm volatile("s_waitcnt vmcnt(6)" ::: "memory")
#define VM0   asm volatile("s_waitcnt vmcnt(0)" ::: "memory")
#define PRI1  __builtin_amdgcn_s_setprio(1)
#define PRI0  __builtin_amdgcn_s_setprio(0)

    f32x4 acc[8][4];
#pragma unroll
    for (int m = 0; m < 8; ++m)
#pragma unroll
        for (int n = 0; n < 4; ++n) acc[m][n] = (f32x4){0.f, 0.f, 0.f, 0.f};

    bf16x8 af[4][2], bf0[2][2], bf1[2][2];

    // prologue: K0 full + K1 {Ah0,Bh0,Bh1}  (Ah1(1) staged at P1 of iter 0)
    STG_A(0, 0, 0); STG_B(0, 0, 0); STG_A(0, 1, 0); STG_B(0, 1, 0);
    STG_A(1, 0, 1); STG_B(1, 0, 1); STG_B(1, 1, 1);
    VM6; LGKM0; BAR;    // K0's 4 halves (oldest 8 loads) landed; tokS visible

    for (int i = 0; i < NIT; ++i) {
        int kt1 = 2 * i + 1;
        int n0  = 2 * i + 2;    // next even K-tile -> buf0
        int n1  = 2 * i + 3;    // next odd  K-tile -> buf1
        bool lastIt = (i == NIT - 1);

        // ---- P1: read mh0+nh0 of buf0; stage Ah1(kt1) ----
        LDA(0, 0); LDB(bf0, 0, 0);
        STG_A(1, 1, kt1);
        BAR; LGKM0; PRI1; MM(0, 0, bf0); PRI0; BAR;
        // ---- P2: read nh1 of buf0; stage Ah0(n0) ----
        LDB(bf1, 1, 0);
        STG_A(0, 0, n0);
        BAR; LGKM0; PRI1; MM(0, 1, bf1); PRI0; BAR;
        // ---- P3: read mh1 of buf0; stage Bh0(n0) ----
        LDA(1, 0);
        STG_B(0, 0, n0);
        BAR; LGKM0; PRI1; MM(1, 0, bf0); PRI0; BAR;
        // ---- P4: stage Ah1(n0); counted wait ----
        STG_A(0, 1, n0);
        if (lastIt) { VM0; } else { VM6; }
        BAR; PRI1; MM(1, 1, bf1); PRI0; BAR;
        // ---- P5: read mh0+nh0 of buf1; stage Bh1(n0) ----
        LDA(0, 1); LDB(bf0, 0, 1);
        STG_B(0, 1, n0);
        BAR; LGKM0; PRI1; MM(0, 0, bf0); PRI0; BAR;
        // ---- P6: read nh1 of buf1; stage Ah0(n1) ----
        LDB(bf1, 1, 1);
        STG_A(1, 0, n1);
        BAR; LGKM0; PRI1; MM(0, 1, bf1); PRI0; BAR;
        // ---- P7: read mh1 of buf1; stage Bh0(n1) ----
        LDA(1, 1);
        STG_B(1, 0, n1);
        BAR; LGKM0; PRI1; MM(1, 0, bf0); PRI0; BAR;
        // ---- P8: stage Bh1(n1); counted wait ----
        STG_B(1, 1, n1);
        if (!lastIt) { VM6; }
        BAR; PRI1; MM(1, 1, bf1); PRI0; BAR;
    }

#undef GLL
#undef STG_A
#undef STG_B
#undef LDA
#undef LDB
#undef MM

    // epilogue: weighted atomic scatter (each out element receives exactly 2 adds)
#pragma unroll
    for (int m = 0; m < 8; ++m) {
#pragma unroll
        for (int jj = 0; jj < 4; ++jj) {
            int row = m * 32 + wr * 16 + fq * 4 + jj;
            int tok = tokS[row];
            if (tok < 0) continue;
            float wgt = wS[row];
            float* orow = out + (size_t)tok * NEMB + cb * BN + wc * 16 + fr;
#pragma unroll
            for (int n = 0; n < 4; ++n)
                unsafeAtomicAdd(orow + n * 64, wgt * acc[m][n][jj]);
        }
    }
}

extern "C" void kernel_launch(void* const* d_in, const int* in_sizes, int n_in,
                              void* d_out, int out_size, void* d_ws, size_t ws_size,
                              hipStream_t stream) {
    const float* x  = (const float*)d_in[0];
    const float* gw = (const float*)d_in[1];
    const float* ew = (const float*)d_in[2];
    float* out = (float*)d_out;

    char* ws = (char*)d_ws;
    unsigned short* xb = (unsigned short*)(ws);
    unsigned short* wb = (unsigned short*)(ws + XB_BYTES);
    int*   counts = (int*)(ws + CNT_OFF);
    int*   ltok   = (int*)(ws + LTOK_OFF);
    float* lwt    = (float*)(ws + LWT_OFF);
    int4*  selw   = (int4*)(ws + SELW_OFF);

    hipMemsetAsync(counts, 0, 8 * sizeof(int), stream);
    hipMemsetAsync(out, 0, (size_t)NTOK * NEMB * sizeof(float), stream);

    k_cvt_w<<<4096, 256, 0, stream>>>(ew, wb);
    k_gate<<<NTOK / 4, 256, 0, stream>>>(x, gw, xb, selw);
    k_build<<<dim3(NTOK / BLD_STRIPE, NEXP), 256, 0, stream>>>(selw, counts, ltok, lwt);
    k_pad<<<8, 128, 0, stream>>>(counts, ltok, lwt);
    // grid: 4 cb x 16 rb slots x 8 experts = 512 blocks (~256 active, 1/CU)
    k_gemm<<<dim3(NEMB / BN, 16, NEXP), 512, 0, stream>>>(xb, wb, counts, ltok, lwt, out);
}